// Round 8
// baseline (1568.178 us; speedup 1.0000x reference)
//
#include <hip/hip_runtime.h>
#include <math.h>

typedef short v8s __attribute__((ext_vector_type(8)));
typedef float v4f __attribute__((ext_vector_type(4)));

// ---------------- fp32 direct conv (layers 1,17,18) --------------------------------
template<int K, int COT, bool POOL, bool MASK, bool SWAP>
__global__ __launch_bounds__(256) void conv_fused(
    const float* __restrict__ in, const float* __restrict__ wgt,
    const float* __restrict__ bias, float* __restrict__ out,
    int B, int Cin, int Hin, int Win,
    int Hc, int Wc, int Hout, int Wout,
    int Cout, int cpad, int ppad,
    int inPS, int inRS, int inOfs, int outPS, int outRS, int outOfs)
{
    constexpr int NPY = POOL ? 2 : 1;
    constexpr int PS  = K + NPY - 1;
    const int spatial = Hout * Wout;
    const int idx = (SWAP ? blockIdx.y : blockIdx.x) * blockDim.x + threadIdx.x;
    const int cog = SWAP ? blockIdx.x : blockIdx.y;
    const int total = B * spatial;
    if (idx >= total) return;
    const int b  = idx / spatial;
    const int sp = idx - b * spatial;
    const int oy = sp / Wout;
    const int ox = sp - oy * Wout;
    const int co0 = cog * COT;

    const int cy0 = POOL ? (2 * oy - ppad) : oy;
    const int cx0 = POOL ? (2 * ox - ppad) : ox;
    const int iy0 = cy0 - cpad;
    const int ix0 = cx0 - cpad;

    bool my[PS], mx[PS];
#pragma unroll
    for (int i = 0; i < PS; i++) {
        my[i] = !MASK || ((unsigned)(iy0 + i) < (unsigned)Hin);
        mx[i] = !MASK || ((unsigned)(ix0 + i) < (unsigned)Win);
    }

    float acc[COT][NPY * NPY];
#pragma unroll
    for (int c = 0; c < COT; c++)
#pragma unroll
        for (int p = 0; p < NPY * NPY; p++) acc[c][p] = 0.f;

    const float* inB = in + inOfs + (size_t)b * Cin * inPS;
    const long wBase  = (long)co0 * Cin * K * K;

    for (int ci = 0; ci < Cin; ci++) {
        const float* ip = inB + (size_t)ci * inPS;
        float patch[PS][PS];
#pragma unroll
        for (int py = 0; py < PS; py++) {
#pragma unroll
            for (int px = 0; px < PS; px++) {
                float v = 0.f;
                if (my[py] && mx[px]) v = ip[(iy0 + py) * inRS + (ix0 + px)];
                patch[py][px] = v;
            }
        }
        const float* wp = wgt + wBase + (long)ci * K * K;
#pragma unroll
        for (int c = 0; c < COT; c++) {
#pragma unroll
            for (int kh = 0; kh < K; kh++)
#pragma unroll
            for (int kw = 0; kw < K; kw++) {
                const float wv = wp[(long)c * Cin * K * K + kh * K + kw];
#pragma unroll
                for (int dy = 0; dy < NPY; dy++)
#pragma unroll
                for (int dx = 0; dx < NPY; dx++)
                    acc[c][dy * NPY + dx] = fmaf(wv, patch[dy + kh][dx + kw],
                                                 acc[c][dy * NPY + dx]);
            }
        }
    }

#pragma unroll
    for (int c = 0; c < COT; c++) {
        float v;
        if (POOL) {
            v = -INFINITY;
#pragma unroll
            for (int dy = 0; dy < NPY; dy++)
#pragma unroll
            for (int dx = 0; dx < NPY; dx++) {
                const int cy = cy0 + dy, cx = cx0 + dx;
                if ((unsigned)cy < (unsigned)Hc && (unsigned)cx < (unsigned)Wc)
                    v = fmaxf(v, acc[c][dy * NPY + dx]);
            }
        } else {
            v = acc[c][0];
        }
        v += bias[co0 + c];
        out[outOfs + (size_t)(b * Cout + co0 + c) * outPS + oy * outRS + ox] = v;
    }
}

// ---------------- ring zero --------------------------------------------------------
__global__ __launch_bounds__(256) void ring_zero(
    float* __restrict__ buf, int planes, int H, int W)
{
    int Wp = W + 2, Hp = H + 2;
    int ringlen = 2 * Wp + 2 * H;
    int t = blockIdx.x * 256 + threadIdx.x;
    if (t >= planes * ringlen) return;
    int p = t / ringlen, r = t - p * ringlen;
    float* pl = buf + (size_t)p * Hp * Wp;
    int idx;
    if (r < Wp) idx = r;
    else if (r < 2 * Wp) idx = (Hp - 1) * Wp + (r - Wp);
    else { int rr = r - 2 * Wp; int row = 1 + (rr >> 1); idx = row * Wp + ((rr & 1) ? (Wp - 1) : 0); }
    pl[idx] = 0.f;
}

// ---------------- weight prepack ---------------------------------------------------
__device__ __forceinline__ unsigned short f2bf_rne(float x) {
    unsigned u = __float_as_uint(x);
    return (unsigned short)((u + 0x7fffu + ((u >> 16) & 1u)) >> 16);
}
__device__ __forceinline__ float bf2f(unsigned short h) {
    return __uint_as_float(((unsigned)h) << 16);
}

__global__ __launch_bounds__(256) void prepack(
    const float* __restrict__ w, unsigned short* __restrict__ hi,
    unsigned short* __restrict__ lo, int cout, int kdim, int nkb)
{
    int t = blockIdx.x * 256 + threadIdx.x;
    if (t >= cout * kdim) return;
    int co = t / kdim, k = t - co * kdim;
    int cb = co >> 4, m = co & 15, kb = k >> 5, kk = k & 31;
    int lane = ((kk >> 3) << 4) | m, j = kk & 7;
    long dst = ((long)(cb * nkb + kb) << 9) + lane * 8 + j;
    float x = w[t];
    unsigned short h = f2bf_rne(x);
    hi[dst] = h;
    lo[dst] = f2bf_rne(x - bf2f(h));
}

// ---------------- N64 implicit-GEMM conv via MFMA, bf16x2 3-pass -------------------
// Ring-padded input; packed b32 LDS writes.
// DEEP=false: 2-buffer LDS, prefetch distance 1 (low VGPR, for big grids).
// DEEP=true : 3-buffer LDS, gather prefetch distance 2, register-double-buffered
//             weights (for grid-starved layers where VGPRs are free).
template<int MT, int KS, bool SPLIT, bool DEEP>
__global__ __launch_bounds__(256) void conv_mfma(
    const float* __restrict__ in, const unsigned short* __restrict__ whi,
    const unsigned short* __restrict__ wlo, const float* __restrict__ bias,
    float* __restrict__ out, int Cin, int inHWp, int inWp, int Hc, int Wc,
    int Cout, int pad, int b0, int nb, int nkbTot, int nkbPer, int Mpad,
    int outHWp, int outWp)
{
    const int HW = Hc * Wc;
    const int M = nb * HW;
    const int tid = threadIdx.x;
    const int lane = tid & 63;
    const int wv = tid >> 6;
    const int spBase = blockIdx.x * 64;
    const int kb0 = SPLIT ? blockIdx.z * nkbPer : 0;
    const int kb1 = SPLIT ? kb0 + nkbPer : nkbTot;
    const int n = kb1 - kb0;

    __shared__ unsigned short P[DEEP ? 3 : 2][5120]; // hi @0, lo @2560; stride 40

    const int spo = lane >> 2;              // 16 spatial slots per wave
    const int kp  = (tid & 3) + 4 * wv;     // k-pair owner: k = 2kp, 2kp+1

    int jbase[4];
#pragma unroll
    for (int j = 0; j < 4; ++j) {
        int sp = spBase + spo + 16 * j;
        int q = sp < M ? sp : M - 1;
        int b = q / HW; int r = q - b * HW;
        int soy = r / Wc, sox = r - soy * Wc;
        jbase[j] = (b0 + b) * Cin * inHWp + (soy + 1) * inWp + (sox + 1);
    }

    int ci[2], r9[2], koff[2];
#pragma unroll
    for (int m = 0; m < 2; ++m) {
        int k = kb0 * 32 + 2 * kp + m;
        if (KS == 3) {
            ci[m] = k / 9; r9[m] = k - 9 * ci[m];
            int d3 = (r9[m] >= 3) + (r9[m] >= 6);
            koff[m] = ci[m] * inHWp + (d3 - pad) * inWp + (r9[m] - 3 * d3 - pad);
        } else { ci[m] = k; koff[m] = k * inHWp; }
    }

#define STAGE(RV)                                                              \
    {                                                                          \
        _Pragma("unroll")                                                      \
        for (int m = 0; m < 2; ++m)                                            \
        _Pragma("unroll")                                                      \
        for (int j = 0; j < 4; ++j)                                            \
            RV[m * 4 + j] = in[jbase[j] + koff[m]];                            \
    }
#define ADV()                                                                  \
    {                                                                          \
        _Pragma("unroll")                                                      \
        for (int m = 0; m < 2; ++m) {                                          \
            if (KS == 3) {                                                     \
                r9[m] += 5; int c_ = r9[m] >= 9; r9[m] -= c_ ? 9 : 0;          \
                ci[m] += 3 + c_;                                               \
                int d3 = (r9[m] >= 3) + (r9[m] >= 6);                          \
                koff[m] = ci[m] * inHWp + (d3 - pad) * inWp                    \
                        + (r9[m] - 3 * d3 - pad);                              \
            } else { koff[m] += 32 * inHWp; }                                  \
        }                                                                      \
    }
#define LDSW(PL, RV)                                                           \
    {                                                                          \
        _Pragma("unroll")                                                      \
        for (int j = 0; j < 4; ++j) {                                          \
            unsigned vb0 = __float_as_uint(RV[j]);                             \
            unsigned vb1 = __float_as_uint(RV[4 + j]);                         \
            unsigned hiP = (vb0 >> 16) | (vb1 & 0xffff0000u);                  \
            float r0 = RV[j]     - __uint_as_float(vb0 & 0xffff0000u);         \
            float r1 = RV[4 + j] - __uint_as_float(vb1 & 0xffff0000u);         \
            unsigned loP = (__float_as_uint(r0) >> 16)                         \
                         | (__float_as_uint(r1) & 0xffff0000u);                \
            int a = (spo + 16 * j) * 40 + 2 * kp;                              \
            *(unsigned*)((PL) + a) = hiP;                                      \
            *(unsigned*)((PL) + 2560 + a) = loP;                               \
        }                                                                      \
    }
#define MFMAPH(PL, WH, WL)                                                     \
    {                                                                          \
        _Pragma("unroll")                                                      \
        for (int nt = 0; nt < 4; ++nt) {                                       \
            int ro = (nt * 16 + (lane & 15)) * 40 + (lane >> 4) * 8;           \
            v8s ph = *(const v8s*)((PL) + ro);                                 \
            v8s pl = *(const v8s*)((PL) + 2560 + ro);                          \
            _Pragma("unroll")                                                  \
            for (int mt = 0; mt < MT; ++mt) {                                  \
                acc[mt][nt] = __builtin_amdgcn_mfma_f32_16x16x32_bf16(         \
                    WH[mt], ph, acc[mt][nt], 0, 0, 0);                         \
                acc[mt][nt] = __builtin_amdgcn_mfma_f32_16x16x32_bf16(         \
                    WH[mt], pl, acc[mt][nt], 0, 0, 0);                         \
                acc[mt][nt] = __builtin_amdgcn_mfma_f32_16x16x32_bf16(         \
                    WL[mt], ph, acc[mt][nt], 0, 0, 0);                         \
            }                                                                  \
        }                                                                      \
    }
#define WLOADTO(WH, WL)                                                        \
    {                                                                          \
        _Pragma("unroll")                                                      \
        for (int mt = 0; mt < MT; ++mt) {                                      \
            WH[mt] = *(const v8s*)whp[mt]; whp[mt] += 512;                     \
            WL[mt] = *(const v8s*)wlp[mt]; wlp[mt] += 512;                     \
        }                                                                      \
    }

    const int g0 = blockIdx.y * (MT * 4) + wv * MT;
    const unsigned short* whp[MT];
    const unsigned short* wlp[MT];
#pragma unroll
    for (int mt = 0; mt < MT; ++mt) {
        size_t base = (((size_t)(g0 + mt) * nkbTot + kb0) << 9) + lane * 8;
        whp[mt] = whi + base; wlp[mt] = wlo + base;
    }

    v4f acc[MT][4];
    {
        v4f z = {0.f, 0.f, 0.f, 0.f};
#pragma unroll
        for (int mt = 0; mt < MT; ++mt)
#pragma unroll
            for (int nt = 0; nt < 4; ++nt) acc[mt][nt] = z;
    }

    if (DEEP) {
        float rv0[8], rv1[8];
        STAGE(rv0); ADV();                      // chunk 0
        if (n > 1) { STAGE(rv1); ADV(); }       // chunk 1
        LDSW(&P[0][0], rv0);                    // chunk 0 -> buf0
        if (n > 2) { STAGE(rv0); ADV(); }       // chunk 2
        v8s whA[MT], wlA[MT], whB[MT], wlB[MT];
        WLOADTO(whA, wlA);                      // weights chunk 0
        __syncthreads();
        int br = 0, bw = 1;
#define ITER(C, WC, LC, WN, LN, RVX)                                           \
        {                                                                      \
            unsigned short* Pw = &P[bw][0];                                    \
            if ((C) + 1 < n) LDSW(Pw, RVX);                                    \
            if ((C) + 3 < n) { STAGE(RVX); ADV(); }                            \
            if ((C) + 1 < n) { WLOADTO(WN, LN); }                              \
            __syncthreads();                                                   \
            unsigned short* Pr = &P[br][0];                                    \
            MFMAPH(Pr, WC, LC);                                                \
            br = bw; bw = (bw == 2) ? 0 : bw + 1;                              \
        }
        int c = 0;
        for (;;) {
            ITER(c, whA, wlA, whB, wlB, rv1);
            if (++c >= n) break;
            ITER(c, whB, wlB, whA, wlA, rv0);
            if (++c >= n) break;
        }
#undef ITER
    } else {
        float rv[8];
        STAGE(rv);
        for (int cc = 0; cc < n; ++cc) {
            unsigned short* Pl = &P[cc & 1][0];
            LDSW(Pl, rv);
            __syncthreads();
            v8s wh[MT], wl[MT];
            WLOADTO(wh, wl);
            if (cc + 1 < n) { ADV(); STAGE(rv); }   // overlaps MFMA below
            MFMAPH(Pl, wh, wl);
        }
    }
#undef STAGE
#undef ADV
#undef LDSW
#undef MFMAPH
#undef WLOADTO

    const int qrow = (lane >> 4) * 4;
    if (SPLIT) {
        float* pz = out + (size_t)blockIdx.z * Cout * Mpad;
#pragma unroll
        for (int mt = 0; mt < MT; ++mt) {
            int co = (g0 + mt) * 16 + qrow;
#pragma unroll
            for (int nt = 0; nt < 4; ++nt) {
                int sp = spBase + nt * 16 + (lane & 15);
                if (sp < M) {
#pragma unroll
                    for (int r = 0; r < 4; ++r)
                        pz[(size_t)(co + r) * Mpad + sp] = acc[mt][nt][r];
                }
            }
        }
    } else {
#pragma unroll
        for (int mt = 0; mt < MT; ++mt) {
            int co = (g0 + mt) * 16 + qrow;
            float bsv[4];
#pragma unroll
            for (int r = 0; r < 4; ++r) bsv[r] = bias[co + r];
#pragma unroll
            for (int nt = 0; nt < 4; ++nt) {
                int sp = spBase + nt * 16 + (lane & 15);
                if (sp < M) {
                    int b = sp / HW, rsp = sp - b * HW;
                    int y = rsp / Wc, xx = rsp - y * Wc;
                    float* op = out + (size_t)(b * Cout + co) * outHWp
                              + (size_t)(y + 1) * outWp + (xx + 1);
#pragma unroll
                    for (int r = 0; r < 4; ++r)
                        op[(size_t)r * outHWp] = acc[mt][nt][r] + bsv[r];
                }
            }
        }
    }
}

// ---------------- N128 variant: 128-spatial C-tile, waves split couts --------------
// For big-M layers (cout<=128). Single 20KB LDS buffer, 2 barriers/chunk.
// Couts per block = MT*4*16; grid (ceil(M/128), Cout/(MT*64)).
template<int MT, int KS>
__global__ __launch_bounds__(256) void conv_mfma_n128(
    const float* __restrict__ in, const unsigned short* __restrict__ whi,
    const unsigned short* __restrict__ wlo, const float* __restrict__ bias,
    float* __restrict__ out, int Cin, int inHWp, int inWp, int Hc, int Wc,
    int Cout, int pad, int b0, int nb, int nkbTot, int outHWp, int outWp)
{
    const int HW = Hc * Wc;
    const int M = nb * HW;
    const int tid = threadIdx.x;
    const int lane = tid & 63;
    const int wv = tid >> 6;
    const int spBase = blockIdx.x * 128;

    __shared__ unsigned short P[10240];     // hi rows[128] @0, lo @5120; stride 40

    const int spo = lane >> 2;              // 16 spatial slots per wave-quarter
    const int kp  = (tid & 3) + 4 * wv;     // k-pair owner: k = 2kp, 2kp+1

    int jbase[8];
#pragma unroll
    for (int j = 0; j < 8; ++j) {
        int sp = spBase + spo + 16 * j;
        int q = sp < M ? sp : M - 1;
        int b = q / HW; int r = q - b * HW;
        int soy = r / Wc, sox = r - soy * Wc;
        jbase[j] = (b0 + b) * Cin * inHWp + (soy + 1) * inWp + (sox + 1);
    }

    int ci[2], r9[2], koff[2];
#pragma unroll
    for (int m = 0; m < 2; ++m) {
        int k = 2 * kp + m;
        if (KS == 3) {
            ci[m] = k / 9; r9[m] = k - 9 * ci[m];
            int d3 = (r9[m] >= 3) + (r9[m] >= 6);
            koff[m] = ci[m] * inHWp + (d3 - pad) * inWp + (r9[m] - 3 * d3 - pad);
        } else { ci[m] = k; koff[m] = k * inHWp; }
    }

    float rv[16];
#pragma unroll
    for (int m = 0; m < 2; ++m)
#pragma unroll
    for (int j = 0; j < 8; ++j)
        rv[m * 8 + j] = in[jbase[j] + koff[m]];

    const int g0 = blockIdx.y * (MT * 4) + wv * MT;
    const unsigned short* whp[MT];
    const unsigned short* wlp[MT];
#pragma unroll
    for (int mt = 0; mt < MT; ++mt) {
        size_t base = ((size_t)(g0 + mt) * nkbTot << 9) + lane * 8;
        whp[mt] = whi + base; wlp[mt] = wlo + base;
    }

    v4f acc[MT][8];
    {
        v4f z = {0.f, 0.f, 0.f, 0.f};
#pragma unroll
        for (int mt = 0; mt < MT; ++mt)
#pragma unroll
            for (int nt = 0; nt < 8; ++nt) acc[mt][nt] = z;
    }

    for (int cc = 0; cc < nkbTot; ++cc) {
#pragma unroll
        for (int j = 0; j < 8; ++j) {
            unsigned vb0 = __float_as_uint(rv[j]);
            unsigned vb1 = __float_as_uint(rv[8 + j]);
            unsigned hiP = (vb0 >> 16) | (vb1 & 0xffff0000u);
            float r0 = rv[j]     - __uint_as_float(vb0 & 0xffff0000u);
            float r1 = rv[8 + j] - __uint_as_float(vb1 & 0xffff0000u);
            unsigned loP = (__float_as_uint(r0) >> 16)
                         | (__float_as_uint(r1) & 0xffff0000u);
            int a = (spo + 16 * j) * 40 + 2 * kp;
            *(unsigned*)(P + a) = hiP;
            *(unsigned*)(P + 5120 + a) = loP;
        }
        __syncthreads();

        v8s wh[MT], wl[MT];
#pragma unroll
        for (int mt = 0; mt < MT; ++mt) {
            wh[mt] = *(const v8s*)whp[mt]; whp[mt] += 512;
            wl[mt] = *(const v8s*)wlp[mt]; wlp[mt] += 512;
        }

        if (cc + 1 < nkbTot) {   // advance + prefetch next chunk (overlaps MFMA)
#pragma unroll
            for (int m = 0; m < 2; ++m) {
                if (KS == 3) {
                    r9[m] += 5; int c_ = r9[m] >= 9; r9[m] -= c_ ? 9 : 0;
                    ci[m] += 3 + c_;
                    int d3 = (r9[m] >= 3) + (r9[m] >= 6);
                    koff[m] = ci[m] * inHWp + (d3 - pad) * inWp
                            + (r9[m] - 3 * d3 - pad);
                } else { koff[m] += 32 * inHWp; }
            }
#pragma unroll
            for (int m = 0; m < 2; ++m)
#pragma unroll
            for (int j = 0; j < 8; ++j)
                rv[m * 8 + j] = in[jbase[j] + koff[m]];
        }

#pragma unroll
        for (int nt = 0; nt < 8; ++nt) {
            int ro = (nt * 16 + (lane & 15)) * 40 + (lane >> 4) * 8;
            v8s ph = *(const v8s*)(P + ro);
            v8s pl = *(const v8s*)(P + 5120 + ro);
#pragma unroll
            for (int mt = 0; mt < MT; ++mt) {
                acc[mt][nt] = __builtin_amdgcn_mfma_f32_16x16x32_bf16(wh[mt], ph, acc[mt][nt], 0, 0, 0);
                acc[mt][nt] = __builtin_amdgcn_mfma_f32_16x16x32_bf16(wh[mt], pl, acc[mt][nt], 0, 0, 0);
                acc[mt][nt] = __builtin_amdgcn_mfma_f32_16x16x32_bf16(wl[mt], ph, acc[mt][nt], 0, 0, 0);
            }
        }
        __syncthreads();   // all reads done before next chunk's LDS writes
    }

    const int qrow = (lane >> 4) * 4;
#pragma unroll
    for (int mt = 0; mt < MT; ++mt) {
        int co = (g0 + mt) * 16 + qrow;
        float bsv[4];
#pragma unroll
        for (int r = 0; r < 4; ++r) bsv[r] = bias[co + r];
#pragma unroll
        for (int nt = 0; nt < 8; ++nt) {
            int sp = spBase + nt * 16 + (lane & 15);
            if (sp < M) {
                int b = sp / HW, rsp = sp - b * HW;
                int y = rsp / Wc, xx = rsp - y * Wc;
                float* op = out + (size_t)(b * Cout + co) * outHWp
                          + (size_t)(y + 1) * outWp + (xx + 1);
#pragma unroll
                for (int r = 0; r < 4; ++r)
                    op[(size_t)r * outHWp] = acc[mt][nt][r] + bsv[r];
            }
        }
    }
}

// ---------------- split-K reduce (adds bias, writes padded) ------------------------
__global__ __launch_bounds__(256) void sk_reduce(
    const float* __restrict__ part, const float* __restrict__ bias,
    float* __restrict__ out, int Cout, int HW, int Wc, int M, int Mpad, int SK,
    int outHWp, int outWp)
{
    int t = blockIdx.x * 256 + threadIdx.x;
    if (t >= Cout * M) return;
    int co = t / M, m = t - co * M;
    float s = bias[co];
    for (int k = 0; k < SK; ++k)
        s += part[((size_t)k * Cout + co) * Mpad + m];
    int b = m / HW, rsp = m - b * HW;
    int y = rsp / Wc, xx = rsp - y * Wc;
    out[(size_t)(b * Cout + co) * outHWp + (size_t)(y + 1) * outWp + (xx + 1)] = s;
}

// ---------------- 2x2/2 maxpool, padded in/out -------------------------------------
__global__ __launch_bounds__(256) void maxpool_k(
    const float* __restrict__ in, float* __restrict__ out,
    int Hc, int Wc, int Hp, int Wp, int p, int total,
    int inHWp, int inWp, int outHWp, int outWp)
{
    int t = blockIdx.x * 256 + threadIdx.x;
    if (t >= total) return;
    int wp2 = Hp * Wp;
    int bc = t / wp2; int r = t - bc * wp2;
    int y = r / Wp, xx = r - y * Wp;
    int y0 = 2 * y - p, x0 = 2 * xx - p;
    const float* ip = in + (size_t)bc * inHWp;
    float v = -INFINITY;
#pragma unroll
    for (int dy = 0; dy < 2; ++dy)
#pragma unroll
    for (int dx = 0; dx < 2; ++dx) {
        int yy = y0 + dy, xc = x0 + dx;
        if ((unsigned)yy < (unsigned)Hc && (unsigned)xc < (unsigned)Wc)
            v = fmaxf(v, ip[(yy + 1) * inWp + (xc + 1)]);
    }
    out[(size_t)bc * outHWp + (size_t)(y + 1) * outWp + (xx + 1)] = v;
}

// ---------------- head -------------------------------------------------------------
__global__ __launch_bounds__(1024) void head_kernel(
    const float* __restrict__ x, float* __restrict__ out, int B)
{
    const int W = 13, H = 13;
    const float gx = 0.567f, gy = 0.469f, gw = 0.206f, gh = 0.53f;
    const int tid = threadIdx.x;
    const int total = B * W * H;
    float lsum = 0.f;
    for (int i = tid; i < total; i += blockDim.x) {
        const int b = i / (W * H);
        const int r = i - b * W * H;
        const int j = r / H;
        const int k = r - j * H;
        float v[6];
#pragma unroll
        for (int c = 0; c < 6; c++) {
            v[c] = x[((b * 6 + c) * H + k) * W + j];
            out[((b * W + j) * H + k) * 6 + c] = v[c];
        }
        const float px = (j + v[2]) / (float)W;
        const float py = (k + v[3]) / (float)H;
        const float pw = expf(v[4]) / (float)W;
        const float ph = expf(v[5]) / (float)H;
        float iw = fminf(px + pw * 0.5f, gx + gw * 0.5f)
                 - fmaxf(px - pw * 0.5f, gx - gw * 0.5f);
        iw = fmaxf(iw, 0.f);
        float ih = fminf(py + ph * 0.5f, gy + gh * 0.5f)
                 - fmaxf(py - ph * 0.5f, gy - gh * 0.5f);
        ih = fmaxf(ih, 0.f);
        const float inter = iw * ih;
        const float iou = inter / (pw * ph + gw * gh - inter);
        const float tx = gx * W - (float)j;
        const float ty = gy * H - (float)k;
        const float tw = logf(gw * W);
        const float th = logf(gh * H);
        const float l1 = fabsf(tx - v[2]) + fabsf(ty - v[3])
                       + fabsf(tw - v[4]) + fabsf(th - v[5]);
        if (iou > 0.5f) lsum += l1;
    }
    __shared__ float red[1024];
    red[tid] = lsum;
    __syncthreads();
    for (int s = blockDim.x / 2; s > 0; s >>= 1) {
        if (tid < s) red[tid] += red[tid + s];
        __syncthreads();
    }
    if (tid == 0) out[total * 6] = red[0];
}

// ---------------- host -------------------------------------------------------------
extern "C" void kernel_launch(void* const* d_in, const int* in_sizes, int n_in,
                              void* d_out, int out_size, void* d_ws, size_t ws_size,
                              hipStream_t stream)
{
    (void)in_sizes; (void)n_in; (void)out_size;
    const float* x = (const float*)d_in[0];
    const int B = 16;
    const size_t MB = 1024 * 1024;
    char* ws = (char*)d_ws;
    float* bufA = (float*)ws;                                  // <= 93 MB (padded)
    float* bufB = (float*)(ws + 93 * MB);                      // <= 48 MB (padded)
    unsigned short* WHI = (unsigned short*)(ws + 141 * MB);    // <= 12 MB
    unsigned short* WLO = (unsigned short*)(ws + 153 * MB);    // <= 12 MB
    char* TEMP = ws + 165 * MB;
    const bool gemmOK = ws_size >= 166 * MB;
    const size_t tempAvail = ws_size > 165 * MB ? ws_size - 165 * MB : 0;

    static const struct { int cin, cout, ks, cpad, pool, ppad; } L[18] = {
        {3,  32, 3, 0, 1, 1}, {32, 64, 3, 0, 1, 1}, {64, 128, 3, 1, 0, 0},
        {128, 64, 1, 0, 0, 0}, {64, 128, 3, 1, 1, 0}, {128, 256, 3, 1, 0, 0},
        {256, 128, 1, 0, 0, 0}, {128, 256, 3, 0, 1, 1}, {256, 512, 3, 1, 0, 0},
        {512, 256, 1, 0, 0, 0}, {256, 512, 3, 1, 0, 0}, {512, 256, 1, 0, 0, 0},
        {256, 512, 3, 0, 1, 1}, {512, 256, 3, 1, 0, 0}, {256, 128, 1, 0, 0, 0},
        {128, 64, 3, 1, 0, 0}, {64, 32, 1, 0, 0, 0}, {32, 6, 3, 1, 0, 0}
    };
    static const bool RING[18] = {0,1,0,1,1,0,0,1,0,1,0,0,1,0,1,0,1,0};

    if (gemmOK) {
        size_t off = 0;
        for (int i = 1; i <= 15; ++i) {
            int kdim = L[i].cin * L[i].ks * L[i].ks;
            int n = L[i].cout * kdim;
            prepack<<<(n + 255) / 256, 256, 0, stream>>>(
                (const float*)d_in[2 * i + 1], WHI + off, WLO + off,
                L[i].cout, kdim, kdim / 32);
            off += (size_t)n;
        }
    }

    const float* cur = x;
    int Hin = 416, Win = 416;
    size_t woff = 0;

    for (int i = 0; i < 18; ++i) {
        const auto& l = L[i];
        const int Hc = Hin + 2 * l.cpad - l.ks + 1;
        const int Wc = Win + 2 * l.cpad - l.ks + 1;
        const int Hout = l.pool ? (Hc + 2 * l.ppad - 2) / 2 + 1 : Hc;
        const int Wout = l.pool ? (Wc + 2 * l.ppad - 2) / 2 + 1 : Wc;
        float* dst = (i % 2 == 0) ? bufA : bufB;
        const float* w  = (const float*)d_in[2 * i + 1];
        const float* bb = (const float*)d_in[2 * i + 2];
        const int kdim = l.cin * l.ks * l.ks;
        const int nkb = kdim / 32;

        const int inRS  = (i == 0) ? Win : (Win + 2);
        const int inPS  = (i == 0) ? Hin * Win : (Hin + 2) * (Win + 2);
        const int inOfs = (i == 0) ? 0 : (inRS + 1);
        const bool outPad = (i != 17);
        const int outRS  = outPad ? (Wout + 2) : Wout;
        const int outPS  = outPad ? (Hout + 2) * (Wout + 2) : Hout * Wout;
        const int outOfs = outPad ? (outRS + 1) : 0;
        const int tRS = Wc + 2, tPS = (Hc + 2) * (Wc + 2);

        if (RING[i]) {
            int planes = B * l.cout;
            int ringlen = 2 * (Wout + 2) + 2 * Hout;
            ring_zero<<<(planes * ringlen + 255) / 256, 256, 0, stream>>>(
                dst, planes, Hout, Wout);
        }

        int nb = 16;
        if (l.pool) {
            size_t perImg = (size_t)l.cout * tPS * 4;
            while (nb && perImg * (size_t)nb > tempAvail) nb >>= 1;
        }
        const bool useG = gemmOK && i >= 1 && i <= 15 && (!l.pool || nb >= 1);

        if (useG) {
            for (int b0 = 0; b0 < B; b0 += nb) {
                const int M = nb * Hc * Wc;
                float* poolout = l.pool ? (float*)TEMP : dst;
                const int pHWp = l.pool ? tPS : outPS;
                const int pWp  = l.pool ? tRS : outRS;
                const bool n128 = (l.cout <= 128) && ((M + 127) / 128 >= 1024);

                if (n128) {
                    const int gx = (M + 127) / 128;
                    const int MTn = (l.cout >= 128) ? 2 : 1;
                    dim3 gr(gx, l.cout / (MTn * 64));
#define NL(MTC, KSC)                                                           \
                    conv_mfma_n128<MTC, KSC><<<gr, 256, 0, stream>>>(          \
                        cur, WHI + woff, WLO + woff, bb, poolout, l.cin, inPS, \
                        inRS, Hc, Wc, l.cout, l.cpad, b0, nb, nkb, pHWp, pWp)
                    if (MTn == 2) { if (l.ks == 3) NL(2, 3); else NL(2, 1); }
                    else          { if (l.ks == 3) NL(1, 3); else NL(1, 1); }
#undef NL
                } else {
                    const int gx = (M + 63) / 64;
                    const int Mpad = gx * 64;
                    // MT-reduce first (no HBM partials); restore max MT + SK
                    // only for tiny-M layers where reduction can't reach 512.
                    int MTv = (l.cout >= 256) ? 4 : (l.cout >= 128 ? 2 : 1);
                    int gy = l.cout / (MTv * 64);
                    while (MTv > 1 && (long)gx * gy < 512) {
                        MTv >>= 1; gy = l.cout / (MTv * 64);
                    }
                    int SK = 1;
                    if (!l.pool && (long)gx * gy < 512) {
                        MTv = (l.cout >= 256) ? 4 : (l.cout >= 128 ? 2 : 1);
                        gy = l.cout / (MTv * 64);
                        while ((long)gx * gy * SK < 512 && SK < 16 &&
                               nkb % (SK * 2) == 0 &&
                               (size_t)(SK * 2) * l.cout * (size_t)Mpad * 4 <= tempAvail)
                            SK *= 2;
                    }
                    const bool deep = ((long)gx * gy * SK <= 700);
                    const int nkbPer = nkb / SK;
                    float* gout = (SK > 1) ? (float*)TEMP : poolout;
                    const int gHWp = (SK > 1) ? 0 : pHWp;
                    const int gWp  = (SK > 1) ? 0 : pWp;
                    dim3 gr(gx, gy, SK);
#define GL(MTC, KSC, SPL, DP)                                                  \
                    conv_mfma<MTC, KSC, SPL, DP><<<gr, 256, 0, stream>>>(      \
                        cur, WHI + woff, WLO + woff, bb, gout, l.cin, inPS,    \
                        inRS, Hc, Wc, l.cout, l.cpad, b0, nb, nkb, nkbPer,     \
                        Mpad, gHWp, gWp)
#define G3(MTC, KSC)                                                           \
                    do {                                                       \
                        if (SK > 1) { if (deep) GL(MTC, KSC, true, true);      \
                                      else      GL(MTC, KSC, true, false); }   \
                        else        { if (deep) GL(MTC, KSC, false, true);     \
                                      else      GL(MTC, KSC, false, false); }  \
                    } while (0)
#define G4(MTC) do { if (l.ks == 3) G3(MTC, 3); else G3(MTC, 1); } while (0)
                    if (MTv == 4) G4(4);
                    else if (MTv == 2) G4(2);
                    else G4(1);
#undef G4
#undef G3
#undef GL
                    if (SK > 1) {
                        int tot = l.cout * M;
                        sk_reduce<<<(tot + 255) / 256, 256, 0, stream>>>(
                            (const float*)TEMP, bb, dst, l.cout, Hc * Wc, Wc, M,
                            Mpad, SK, outPS, outRS);
                    }
                }
                if (l.pool) {
                    int total = nb * l.cout * Hout * Wout;
                    maxpool_k<<<(total + 255) / 256, 256, 0, stream>>>(
                        (const float*)TEMP,
                        dst + (size_t)b0 * l.cout * outPS,
                        Hc, Wc, Hout, Wout, l.ppad, total, tPS, tRS, outPS, outRS);
                }
            }
        } else {
            const int spatial = Hout * Wout;
#define FL(KK, CC, PP, MM, SW)                                                 \
            conv_fused<KK, CC, PP, MM, SW><<<                                  \
                SW ? dim3(l.cout / CC, (B * spatial + 255) / 256)              \
                   : dim3((B * spatial + 255) / 256, l.cout / CC),             \
                256, 0, stream>>>(                                             \
                cur, w, bb, dst, B, l.cin, Hin, Win, Hc, Wc, Hout, Wout,       \
                l.cout, l.cpad, l.ppad, inPS, inRS, inOfs, outPS, outRS, outOfs)
            if (i == 0)                           FL(3, 8, true, true, true);
            else if (i == 16)                     FL(1, 8, false, false, false);
            else if (i == 17)                     FL(3, 6, false, false, false);
            else if (l.pool)                      FL(3, 4, true, true, false);
            else if (l.ks == 3)                   FL(3, 8, false, true, false);
            else                                  FL(1, 8, false, true, false);
#undef FL
        }

        if (i >= 1 && i <= 15) woff += (size_t)l.cout * kdim;
        cur = dst;
        Hin = Hout;
        Win = Wout;
    }

    head_kernel<<<1, 1024, 0, stream>>>(cur, (float*)d_out, B);
}

// Round 9
// 1478.155 us; speedup vs baseline: 1.0609x; 1.0609x over previous
//
#include <hip/hip_runtime.h>
#include <math.h>

typedef short v8s __attribute__((ext_vector_type(8)));
typedef float v4f __attribute__((ext_vector_type(4)));
typedef unsigned uu2 __attribute__((ext_vector_type(2)));

// ---------------- generalized-stride fp32 direct conv (layers 0,16,17 + fallback) --
// addr_in  = inOfs  + b*inBS  + ci*inCS + iy*inRS + ix*inXS
// addr_out = outOfs + b*outBS + co*outCS + oy*outRS + ox*outXS
template<int K, int COT, bool POOL, bool MASK, bool SWAP>
__global__ __launch_bounds__(256) void conv_fused(
    const float* __restrict__ in, const float* __restrict__ wgt,
    const float* __restrict__ bias, float* __restrict__ out,
    int B, int Cin, int Hin, int Win,
    int Hc, int Wc, int Hout, int Wout,
    int Cout, int cpad, int ppad,
    long inBS, long inCS, int inRS, int inXS, long inOfs,
    long outBS, long outCS, int outRS, int outXS, long outOfs)
{
    constexpr int NPY = POOL ? 2 : 1;
    constexpr int PS  = K + NPY - 1;
    const int spatial = Hout * Wout;
    const int idx = (SWAP ? blockIdx.y : blockIdx.x) * blockDim.x + threadIdx.x;
    const int cog = SWAP ? blockIdx.x : blockIdx.y;
    const int total = B * spatial;
    if (idx >= total) return;
    const int b  = idx / spatial;
    const int sp = idx - b * spatial;
    const int oy = sp / Wout;
    const int ox = sp - oy * Wout;
    const int co0 = cog * COT;

    const int cy0 = POOL ? (2 * oy - ppad) : oy;
    const int cx0 = POOL ? (2 * ox - ppad) : ox;
    const int iy0 = cy0 - cpad;
    const int ix0 = cx0 - cpad;

    bool my[PS], mx[PS];
#pragma unroll
    for (int i = 0; i < PS; i++) {
        my[i] = !MASK || ((unsigned)(iy0 + i) < (unsigned)Hin);
        mx[i] = !MASK || ((unsigned)(ix0 + i) < (unsigned)Win);
    }

    float acc[COT][NPY * NPY];
#pragma unroll
    for (int c = 0; c < COT; c++)
#pragma unroll
        for (int p = 0; p < NPY * NPY; p++) acc[c][p] = 0.f;

    const float* inB = in + inOfs + (size_t)b * inBS;
    const long wBase = (long)co0 * Cin * K * K;

    for (int ci = 0; ci < Cin; ci++) {
        const float* ip = inB + (size_t)ci * inCS;
        float patch[PS][PS];
#pragma unroll
        for (int py = 0; py < PS; py++) {
#pragma unroll
            for (int px = 0; px < PS; px++) {
                float v = 0.f;
                if (my[py] && mx[px])
                    v = ip[(iy0 + py) * inRS + (ix0 + px) * inXS];
                patch[py][px] = v;
            }
        }
        const float* wp = wgt + wBase + (long)ci * K * K;
#pragma unroll
        for (int c = 0; c < COT; c++) {
#pragma unroll
            for (int kh = 0; kh < K; kh++)
#pragma unroll
            for (int kw = 0; kw < K; kw++) {
                const float wv = wp[(long)c * Cin * K * K + kh * K + kw];
#pragma unroll
                for (int dy = 0; dy < NPY; dy++)
#pragma unroll
                for (int dx = 0; dx < NPY; dx++)
                    acc[c][dy * NPY + dx] = fmaf(wv, patch[dy + kh][dx + kw],
                                                 acc[c][dy * NPY + dx]);
            }
        }
    }

#pragma unroll
    for (int c = 0; c < COT; c++) {
        float v;
        if (POOL) {
            v = -INFINITY;
#pragma unroll
            for (int dy = 0; dy < NPY; dy++)
#pragma unroll
            for (int dx = 0; dx < NPY; dx++) {
                const int cy = cy0 + dy, cx = cx0 + dx;
                if ((unsigned)cy < (unsigned)Hc && (unsigned)cx < (unsigned)Wc)
                    v = fmaxf(v, acc[c][dy * NPY + dx]);
            }
        } else {
            v = acc[c][0];
        }
        v += bias[co0 + c];
        out[outOfs + (size_t)b * outBS + (size_t)(co0 + c) * outCS
            + oy * outRS + ox * outXS] = v;
    }
}

// ---------------- ring zero (NHWC padded [B,Hp,Wp,C]) ------------------------------
__global__ __launch_bounds__(256) void ring_zero(
    float* __restrict__ buf, int B, int H, int W, int C4)
{
    int Wp = W + 2, Hp = H + 2;
    int rl4 = (2 * Wp + 2 * H) * C4;
    int t = blockIdx.x * 256 + threadIdx.x;
    if (t >= B * rl4) return;
    int p = t / rl4, r = t - p * rl4;
    int top = Wp * C4;
    int idx4;
    if (r < top) idx4 = r;
    else if (r < 2 * top) idx4 = (Hp - 1) * Wp * C4 + (r - top);
    else {
        r -= 2 * top;
        int row = 1 + r / (2 * C4);
        int rr = r - (row - 1) * (2 * C4);
        int side = rr / C4;
        int cc = rr - side * C4;
        idx4 = (row * Wp + side * (Wp - 1)) * C4 + cc;
    }
    v4f z = {0.f, 0.f, 0.f, 0.f};
    ((v4f*)buf)[(size_t)p * Hp * Wp * C4 + idx4] = z;
}

// ---------------- weight prepack: OIHW fp32 -> A-frag bf16 hi/lo, k=(off,ci) -------
__device__ __forceinline__ unsigned short f2bf_rne(float x) {
    unsigned u = __float_as_uint(x);
    return (unsigned short)((u + 0x7fffu + ((u >> 16) & 1u)) >> 16);
}
__device__ __forceinline__ float bf2f(unsigned short h) {
    return __uint_as_float(((unsigned)h) << 16);
}

__global__ __launch_bounds__(256) void prepack(
    const float* __restrict__ w, unsigned short* __restrict__ hi,
    unsigned short* __restrict__ lo, int cout, int cin, int ksq, int nkb)
{
    int kdim = cin * ksq;
    int t = blockIdx.x * 256 + threadIdx.x;
    if (t >= cout * kdim) return;
    int co = t / kdim, rem = t - co * kdim;
    int ci = rem / ksq, off = rem - ci * ksq;
    int k = off * cin + ci;                    // NHWC gather order
    int cb = co >> 4, m = co & 15, kb = k >> 5, kk = k & 31;
    int lane = ((kk >> 3) << 4) | m, j = kk & 7;
    long dst = ((long)(cb * nkb + kb) << 9) + lane * 8 + j;
    float x = w[t];
    unsigned short h = f2bf_rne(x);
    hi[dst] = h;
    lo[dst] = f2bf_rne(x - bf2f(h));
}

// ---------------- shared staging helpers (NHWC, float4 gathers) --------------------
#define PACK_LDSW(PL, V, ROW, KQ)                                              \
    {                                                                          \
        unsigned a0 = __float_as_uint((V)[0]), a1 = __float_as_uint((V)[1]);   \
        unsigned a2 = __float_as_uint((V)[2]), a3 = __float_as_uint((V)[3]);   \
        float r0 = (V)[0] - __uint_as_float(a0 & 0xffff0000u);                 \
        float r1 = (V)[1] - __uint_as_float(a1 & 0xffff0000u);                 \
        float r2 = (V)[2] - __uint_as_float(a2 & 0xffff0000u);                 \
        float r3 = (V)[3] - __uint_as_float(a3 & 0xffff0000u);                 \
        uu2 hp, lp;                                                            \
        hp[0] = (a0 >> 16) | (a1 & 0xffff0000u);                               \
        hp[1] = (a2 >> 16) | (a3 & 0xffff0000u);                               \
        lp[0] = (__float_as_uint(r0) >> 16) | (__float_as_uint(r1) & 0xffff0000u); \
        lp[1] = (__float_as_uint(r2) >> 16) | (__float_as_uint(r3) & 0xffff0000u); \
        int a_ = (ROW) * 40 + 4 * (KQ);                                        \
        *(uu2*)((PL) + a_) = hp;                                               \
        *(uu2*)((PL) + (LOHALF) + a_) = lp;                                    \
    }

// ---------------- N64 implicit-GEMM conv (MFMA bf16x2 3-pass), NHWC ---------------
template<int MT, int KS, bool SPLIT>
__global__ __launch_bounds__(256) void conv_mfma(
    const float* __restrict__ in, const unsigned short* __restrict__ whi,
    const unsigned short* __restrict__ wlo, const float* __restrict__ bias,
    float* __restrict__ out, int Cin, int inBS, int inRow, int Hc, int Wc,
    int Cout, int pad, int b0, int nb, int nkbTot, int nkbPer,
    int Mpad, int outBS, int outRow)
{
    const int HW = Hc * Wc;
    const int M = nb * HW;
    const int tid = threadIdx.x;
    const int lane = tid & 63;
    const int wv = tid >> 6;
    const int spBase = blockIdx.x * 64;
    const int kb0 = SPLIT ? blockIdx.z * nkbPer : 0;
    const int n = SPLIT ? nkbPer : nkbTot;

#define LOHALF 2560
    __shared__ unsigned short P[2][5120];   // hi @0, lo @2560; row stride 40 halves

    const int spo = tid >> 3;               // 0..31
    const int kq  = tid & 7;                // owns k = 4kq..4kq+3 (contig channels)

    int jbase[2];
#pragma unroll
    for (int j = 0; j < 2; ++j) {
        int sp = spBase + spo + 32 * j;
        int q = sp < M ? sp : M - 1;
        int b = q / HW; int r = q - b * HW;
        int y = r / Wc, x = r - y * Wc;
        jbase[j] = (b0 + b) * inBS + (y + 1) * inRow + (x + 1) * Cin;
    }

    int koff, rowrem = 0, rowChunks = 0;
    {
        int k0 = kb0 * 32;
        if (KS == 3) {
            int off0 = k0 / Cin;
            int ci0 = k0 - off0 * Cin;
            int dy0 = off0 / 3, dx0 = off0 - 3 * dy0;
            int cinCh = Cin >> 5;
            rowChunks = 3 * cinCh;
            rowrem = rowChunks - (dx0 * cinCh + (ci0 >> 5));
            koff = (dy0 - pad) * inRow + (dx0 - pad) * Cin + ci0 + 4 * kq;
        } else {
            koff = k0 + 4 * kq;
        }
    }

#define STAGE(F)                                                               \
    {                                                                          \
        F[0] = *(const v4f*)(in + jbase[0] + koff);                            \
        F[1] = *(const v4f*)(in + jbase[1] + koff);                            \
    }
#define ADV()                                                                  \
    {                                                                          \
        if (KS == 3 && --rowrem == 0) {                                        \
            rowrem = rowChunks; koff += inRow - 3 * Cin + 32;                  \
        } else koff += 32;                                                     \
    }

    const int g0 = blockIdx.y * (MT * 4) + wv * MT;
    const unsigned short* whp[MT];
    const unsigned short* wlp[MT];
#pragma unroll
    for (int mt = 0; mt < MT; ++mt) {
        size_t base = (((size_t)(g0 + mt) * nkbTot + kb0) << 9) + lane * 8;
        whp[mt] = whi + base; wlp[mt] = wlo + base;
    }

    v4f acc[MT][4];
    {
        v4f z = {0.f, 0.f, 0.f, 0.f};
#pragma unroll
        for (int mt = 0; mt < MT; ++mt)
#pragma unroll
            for (int nt = 0; nt < 4; ++nt) acc[mt][nt] = z;
    }

    v4f rv0[2], rv1[2];
    STAGE(rv0); ADV();
    if (n > 1) { STAGE(rv1); }
    ADV();

#define BODY(RV)                                                               \
    {                                                                          \
        unsigned short* Pl = &P[cc & 1][0];                                    \
        PACK_LDSW(Pl, RV[0], spo, kq);                                         \
        PACK_LDSW(Pl, RV[1], spo + 32, kq);                                    \
        __syncthreads();                                                       \
        v8s wh[MT], wl[MT];                                                    \
        _Pragma("unroll")                                                      \
        for (int mt = 0; mt < MT; ++mt) {                                      \
            wh[mt] = *(const v8s*)whp[mt]; whp[mt] += 512;                     \
            wl[mt] = *(const v8s*)wlp[mt]; wlp[mt] += 512;                     \
        }                                                                      \
        if (cc + 2 < n) { STAGE(RV); ADV(); }                                  \
        _Pragma("unroll")                                                      \
        for (int nt = 0; nt < 4; ++nt) {                                       \
            int ro = (nt * 16 + (lane & 15)) * 40 + (lane >> 4) * 8;           \
            v8s ph = *(const v8s*)(Pl + ro);                                   \
            v8s pl = *(const v8s*)(Pl + LOHALF + ro);                          \
            _Pragma("unroll")                                                  \
            for (int mt = 0; mt < MT; ++mt) {                                  \
                acc[mt][nt] = __builtin_amdgcn_mfma_f32_16x16x32_bf16(         \
                    wh[mt], ph, acc[mt][nt], 0, 0, 0);                         \
                acc[mt][nt] = __builtin_amdgcn_mfma_f32_16x16x32_bf16(         \
                    wh[mt], pl, acc[mt][nt], 0, 0, 0);                         \
                acc[mt][nt] = __builtin_amdgcn_mfma_f32_16x16x32_bf16(         \
                    wl[mt], ph, acc[mt][nt], 0, 0, 0);                         \
            }                                                                  \
        }                                                                      \
    }

    int cc = 0;
    for (;;) {
        BODY(rv0);
        if (++cc >= n) break;
        BODY(rv1);
        if (++cc >= n) break;
    }
#undef BODY
#undef STAGE
#undef ADV
#undef LOHALF

    const int qrow = (lane >> 4) * 4;
    if (SPLIT) {
        float* pz = out + (size_t)blockIdx.z * Mpad * Cout;
#pragma unroll
        for (int mt = 0; mt < MT; ++mt) {
            int co = (g0 + mt) * 16 + qrow;
#pragma unroll
            for (int nt = 0; nt < 4; ++nt) {
                int sp = spBase + nt * 16 + (lane & 15);
                if (sp < M)
                    *(v4f*)(pz + (size_t)sp * Cout + co) = acc[mt][nt];
            }
        }
    } else {
#pragma unroll
        for (int mt = 0; mt < MT; ++mt) {
            int co = (g0 + mt) * 16 + qrow;
            v4f bs = *(const v4f*)(bias + co);
#pragma unroll
            for (int nt = 0; nt < 4; ++nt) {
                int sp = spBase + nt * 16 + (lane & 15);
                if (sp < M) {
                    int b = sp / HW, rsp = sp - b * HW;
                    int y = rsp / Wc, x = rsp - y * Wc;
                    v4f o = acc[mt][nt] + bs;
                    *(v4f*)(out + (size_t)b * outBS + (y + 1) * outRow
                            + (x + 1) * Cout + co) = o;
                }
            }
        }
    }
}

// ---------------- N128 variant (big-M, cout<=128), NHWC ----------------------------
template<int MT, int KS>
__global__ __launch_bounds__(256) void conv_mfma_n128(
    const float* __restrict__ in, const unsigned short* __restrict__ whi,
    const unsigned short* __restrict__ wlo, const float* __restrict__ bias,
    float* __restrict__ out, int Cin, int inBS, int inRow, int Hc, int Wc,
    int Cout, int pad, int b0, int nb, int nkbTot, int outBS, int outRow)
{
    const int HW = Hc * Wc;
    const int M = nb * HW;
    const int tid = threadIdx.x;
    const int lane = tid & 63;
    const int wv = tid >> 6;
    const int spBase = blockIdx.x * 128;

#define LOHALF 5120
    __shared__ unsigned short P[10240];     // hi rows[128] @0, lo @5120; stride 40

    const int spo = tid >> 3;
    const int kq  = tid & 7;

    int jbase[4];
#pragma unroll
    for (int j = 0; j < 4; ++j) {
        int sp = spBase + spo + 32 * j;
        int q = sp < M ? sp : M - 1;
        int b = q / HW; int r = q - b * HW;
        int y = r / Wc, x = r - y * Wc;
        jbase[j] = (b0 + b) * inBS + (y + 1) * inRow + (x + 1) * Cin;
    }

    int koff, rowrem = 0, rowChunks = 0;
    if (KS == 3) {
        int cinCh = Cin >> 5;
        rowChunks = 3 * cinCh;
        rowrem = rowChunks;
        koff = (0 - pad) * inRow + (0 - pad) * Cin + 4 * kq;
    } else {
        koff = 4 * kq;
    }

    v4f rv[4];
#pragma unroll
    for (int j = 0; j < 4; ++j) rv[j] = *(const v4f*)(in + jbase[j] + koff);

    const int g0 = blockIdx.y * (MT * 4) + wv * MT;
    const unsigned short* whp[MT];
    const unsigned short* wlp[MT];
#pragma unroll
    for (int mt = 0; mt < MT; ++mt) {
        size_t base = ((size_t)(g0 + mt) * nkbTot << 9) + lane * 8;
        whp[mt] = whi + base; wlp[mt] = wlo + base;
    }

    v4f acc[MT][8];
    {
        v4f z = {0.f, 0.f, 0.f, 0.f};
#pragma unroll
        for (int mt = 0; mt < MT; ++mt)
#pragma unroll
            for (int nt = 0; nt < 8; ++nt) acc[mt][nt] = z;
    }

    for (int cc = 0; cc < nkbTot; ++cc) {
#pragma unroll
        for (int j = 0; j < 4; ++j)
            PACK_LDSW(P, rv[j], spo + 32 * j, kq);
        __syncthreads();

        v8s wh[MT], wl[MT];
#pragma unroll
        for (int mt = 0; mt < MT; ++mt) {
            wh[mt] = *(const v8s*)whp[mt]; whp[mt] += 512;
            wl[mt] = *(const v8s*)wlp[mt]; wlp[mt] += 512;
        }

        if (cc + 1 < nkbTot) {
            if (KS == 3 && --rowrem == 0) {
                rowrem = rowChunks; koff += inRow - 3 * Cin + 32;
            } else koff += 32;
#pragma unroll
            for (int j = 0; j < 4; ++j)
                rv[j] = *(const v4f*)(in + jbase[j] + koff);
        }

#pragma unroll
        for (int nt = 0; nt < 8; ++nt) {
            int ro = (nt * 16 + (lane & 15)) * 40 + (lane >> 4) * 8;
            v8s ph = *(const v8s*)(P + ro);
            v8s pl = *(const v8s*)(P + LOHALF + ro);
#pragma unroll
            for (int mt = 0; mt < MT; ++mt) {
                acc[mt][nt] = __builtin_amdgcn_mfma_f32_16x16x32_bf16(wh[mt], ph, acc[mt][nt], 0, 0, 0);
                acc[mt][nt] = __builtin_amdgcn_mfma_f32_16x16x32_bf16(wh[mt], pl, acc[mt][nt], 0, 0, 0);
                acc[mt][nt] = __builtin_amdgcn_mfma_f32_16x16x32_bf16(wl[mt], ph, acc[mt][nt], 0, 0, 0);
            }
        }
        __syncthreads();
    }
#undef LOHALF

    const int qrow = (lane >> 4) * 4;
#pragma unroll
    for (int mt = 0; mt < MT; ++mt) {
        int co = (g0 + mt) * 16 + qrow;
        v4f bs = *(const v4f*)(bias + co);
#pragma unroll
        for (int nt = 0; nt < 8; ++nt) {
            int sp = spBase + nt * 16 + (lane & 15);
            if (sp < M) {
                int b = sp / HW, rsp = sp - b * HW;
                int y = rsp / Wc, x = rsp - y * Wc;
                v4f o = acc[mt][nt] + bs;
                *(v4f*)(out + (size_t)b * outBS + (y + 1) * outRow
                        + (x + 1) * Cout + co) = o;
            }
        }
    }
}

// ---------------- split-K reduce (bias add, NHWC out, float4) ----------------------
__global__ __launch_bounds__(256) void sk_reduce(
    const float* __restrict__ part, const float* __restrict__ bias,
    float* __restrict__ out, int Cout, int HW, int Wc, int M, int Mpad, int SK,
    int outBS, int outRow)
{
    int C4 = Cout >> 2;
    int t = blockIdx.x * 256 + threadIdx.x;
    if (t >= M * C4) return;
    int m = t / C4, cq = t - m * C4;
    int co = 4 * cq;
    v4f s = *(const v4f*)(bias + co);
    for (int k = 0; k < SK; ++k)
        s += *(const v4f*)(part + ((size_t)k * Mpad + m) * Cout + co);
    int b = m / HW, rsp = m - b * HW;
    int y = rsp / Wc, x = rsp - y * Wc;
    *(v4f*)(out + (size_t)b * outBS + (y + 1) * outRow + (x + 1) * Cout + co) = s;
}

// ---------------- 2x2/2 maxpool, NHWC padded in/out, float4 ------------------------
__global__ __launch_bounds__(256) void maxpool_k(
    const float* __restrict__ in, float* __restrict__ out,
    int Hc, int Wc, int Hp, int Wp, int p, int total4, int C,
    int inBS, int inRow, int outBS, int outRow, int b0)
{
    int C4 = C >> 2;
    int t = blockIdx.x * 256 + threadIdx.x;
    if (t >= total4) return;
    int cq = t % C4; int rest = t / C4;
    int x = rest % Wp; rest /= Wp;
    int y = rest % Hp; int bl = rest / Hp;
    int y0 = 2 * y - p, x0 = 2 * x - p;
    v4f v = {-INFINITY, -INFINITY, -INFINITY, -INFINITY};
#pragma unroll
    for (int dy = 0; dy < 2; ++dy)
#pragma unroll
    for (int dx = 0; dx < 2; ++dx) {
        int yy = y0 + dy, xc = x0 + dx;
        if ((unsigned)yy < (unsigned)Hc && (unsigned)xc < (unsigned)Wc) {
            v4f u = *(const v4f*)(in + (size_t)bl * inBS + (yy + 1) * inRow
                                  + (xc + 1) * C + 4 * cq);
            v[0] = fmaxf(v[0], u[0]); v[1] = fmaxf(v[1], u[1]);
            v[2] = fmaxf(v[2], u[2]); v[3] = fmaxf(v[3], u[3]);
        }
    }
    *(v4f*)(out + (size_t)(b0 + bl) * outBS + (y + 1) * outRow
            + (x + 1) * C + 4 * cq) = v;
}

// ---------------- head (reads NCHW unpadded final feat) ----------------------------
__global__ __launch_bounds__(1024) void head_kernel(
    const float* __restrict__ x, float* __restrict__ out, int B)
{
    const int W = 13, H = 13;
    const float gx = 0.567f, gy = 0.469f, gw = 0.206f, gh = 0.53f;
    const int tid = threadIdx.x;
    const int total = B * W * H;
    float lsum = 0.f;
    for (int i = tid; i < total; i += blockDim.x) {
        const int b = i / (W * H);
        const int r = i - b * W * H;
        const int j = r / H;
        const int k = r - j * H;
        float v[6];
#pragma unroll
        for (int c = 0; c < 6; c++) {
            v[c] = x[((b * 6 + c) * H + k) * W + j];
            out[((b * W + j) * H + k) * 6 + c] = v[c];
        }
        const float px = (j + v[2]) / (float)W;
        const float py = (k + v[3]) / (float)H;
        const float pw = expf(v[4]) / (float)W;
        const float ph = expf(v[5]) / (float)H;
        float iw = fminf(px + pw * 0.5f, gx + gw * 0.5f)
                 - fmaxf(px - pw * 0.5f, gx - gw * 0.5f);
        iw = fmaxf(iw, 0.f);
        float ih = fminf(py + ph * 0.5f, gy + gh * 0.5f)
                 - fmaxf(py - ph * 0.5f, gy - gh * 0.5f);
        ih = fmaxf(ih, 0.f);
        const float inter = iw * ih;
        const float iou = inter / (pw * ph + gw * gh - inter);
        const float tx = gx * W - (float)j;
        const float ty = gy * H - (float)k;
        const float tw = logf(gw * W);
        const float th = logf(gh * H);
        const float l1 = fabsf(tx - v[2]) + fabsf(ty - v[3])
                       + fabsf(tw - v[4]) + fabsf(th - v[5]);
        if (iou > 0.5f) lsum += l1;
    }
    __shared__ float red[1024];
    red[tid] = lsum;
    __syncthreads();
    for (int s = blockDim.x / 2; s > 0; s >>= 1) {
        if (tid < s) red[tid] += red[tid + s];
        __syncthreads();
    }
    if (tid == 0) out[total * 6] = red[0];
}

// ---------------- host -------------------------------------------------------------
extern "C" void kernel_launch(void* const* d_in, const int* in_sizes, int n_in,
                              void* d_out, int out_size, void* d_ws, size_t ws_size,
                              hipStream_t stream)
{
    (void)in_sizes; (void)n_in; (void)out_size;
    const float* x = (const float*)d_in[0];
    const int B = 16;
    const size_t MB = 1024 * 1024;
    char* ws = (char*)d_ws;
    float* bufA = (float*)ws;                                  // <= 93 MB (padded)
    float* bufB = (float*)(ws + 93 * MB);                      // <= 48 MB (padded)
    unsigned short* WHI = (unsigned short*)(ws + 141 * MB);    // <= 12 MB
    unsigned short* WLO = (unsigned short*)(ws + 153 * MB);    // <= 12 MB
    char* TEMP = ws + 165 * MB;
    const bool gemmOK = ws_size >= 166 * MB;
    const size_t tempAvail = ws_size > 166 * MB ? ws_size - 166 * MB : 0;

    static const struct { int cin, cout, ks, cpad, pool, ppad; } L[18] = {
        {3,  32, 3, 0, 1, 1}, {32, 64, 3, 0, 1, 1}, {64, 128, 3, 1, 0, 0},
        {128, 64, 1, 0, 0, 0}, {64, 128, 3, 1, 1, 0}, {128, 256, 3, 1, 0, 0},
        {256, 128, 1, 0, 0, 0}, {128, 256, 3, 0, 1, 1}, {256, 512, 3, 1, 0, 0},
        {512, 256, 1, 0, 0, 0}, {256, 512, 3, 1, 0, 0}, {512, 256, 1, 0, 0, 0},
        {256, 512, 3, 0, 1, 1}, {512, 256, 3, 1, 0, 0}, {256, 128, 1, 0, 0, 0},
        {128, 64, 3, 1, 0, 0}, {64, 32, 1, 0, 0, 0}, {32, 6, 3, 1, 0, 0}
    };
    static const bool RING[18] = {0,1,0,1,1,0,0,1,0,1,0,0,1,0,1,0,1,0};

    if (gemmOK) {
        size_t off = 0;
        for (int i = 1; i <= 15; ++i) {
            int kdim = L[i].cin * L[i].ks * L[i].ks;
            int n = L[i].cout * kdim;
            prepack<<<(n + 255) / 256, 256, 0, stream>>>(
                (const float*)d_in[2 * i + 1], WHI + off, WLO + off,
                L[i].cout, L[i].cin, L[i].ks * L[i].ks, kdim / 32);
            off += (size_t)n;
        }
    }

    const float* cur = x;
    int Hin = 416, Win = 416;
    size_t woff = 0;

    for (int i = 0; i < 18; ++i) {
        const auto& l = L[i];
        const int Hc = Hin + 2 * l.cpad - l.ks + 1;
        const int Wc = Win + 2 * l.cpad - l.ks + 1;
        const int Hout = l.pool ? (Hc + 2 * l.ppad - 2) / 2 + 1 : Hc;
        const int Wout = l.pool ? (Wc + 2 * l.ppad - 2) / 2 + 1 : Wc;
        float* dst = (i % 2 == 0) ? bufA : bufB;
        const float* w  = (const float*)d_in[2 * i + 1];
        const float* bb = (const float*)d_in[2 * i + 2];
        const int kdim = l.cin * l.ks * l.ks;
        const int nkb = kdim / 32;

        // NHWC strides (inputs i>=1; outputs i<=16 padded NHWC; i17 NCHW unpadded)
        const int inRow = (Win + 2) * l.cin;
        const int inBS  = (Hin + 2) * inRow;
        const int outRow = (Wout + 2) * l.cout;
        const int outBS  = (Hout + 2) * outRow;
        const int tRow = (Wc + 2) * l.cout;
        const int tBS  = (Hc + 2) * tRow;

        if (RING[i]) {
            int rl4 = (2 * (Wout + 2) + 2 * Hout) * (l.cout / 4);
            ring_zero<<<(B * rl4 + 255) / 256, 256, 0, stream>>>(
                dst, B, Hout, Wout, l.cout / 4);
        }

        int nb = 16;
        if (l.pool && i >= 1) {
            size_t perImg = (size_t)tBS * 4;
            while (nb > 1 && perImg * (size_t)nb + MB > tempAvail) nb >>= 1;
            if (perImg + MB > tempAvail) nb = 0;
        }
        const bool useG = gemmOK && i >= 1 && i <= 15 && (!l.pool || nb >= 1);

        if (useG) {
            for (int b0 = 0; b0 < B; b0 += nb) {
                const int M = nb * Hc * Wc;
                float* gout = l.pool ? (float*)TEMP : dst;
                const int gBS  = l.pool ? tBS : outBS;
                const int gRow = l.pool ? tRow : outRow;
                const int gx128 = (M + 127) / 128;
                const bool n128 = (l.cout <= 128) && (gx128 >= 512);

                if (n128) {
                    const int MTn = (l.cout >= 128) ? 2 : 1;
                    dim3 gr(gx128, l.cout / (MTn * 64));
#define NL(MTC, KSC)                                                           \
                    conv_mfma_n128<MTC, KSC><<<gr, 256, 0, stream>>>(          \
                        cur, WHI + woff, WLO + woff, bb, gout, l.cin, inBS,    \
                        inRow, Hc, Wc, l.cout, l.cpad, b0, nb, nkb, gBS, gRow)
                    if (MTn == 2) { if (l.ks == 3) NL(2, 3); else NL(2, 1); }
                    else          { if (l.ks == 3) NL(1, 3); else NL(1, 1); }
#undef NL
                } else {
                    const int gx = (M + 63) / 64;
                    const int Mpad = gx * 64;
                    int MTv = (l.cout >= 256) ? 4 : (l.cout >= 128 ? 2 : 1);
                    int gy = l.cout / (MTv * 64);
                    while (MTv > 1 && (long)gx * gy < 512) {
                        MTv >>= 1; gy = l.cout / (MTv * 64);
                    }
                    int SK = 1;
                    if (!l.pool && (long)gx * gy < 512) {
                        MTv = (l.cout >= 256) ? 4 : (l.cout >= 128 ? 2 : 1);
                        gy = l.cout / (MTv * 64);
                        while ((long)gx * gy * SK < 512 && SK < 16 &&
                               nkb % (SK * 2) == 0 &&
                               (size_t)(SK * 2) * Mpad * l.cout * 4 + MB <= tempAvail)
                            SK *= 2;
                    }
                    const int nkbPer = nkb / SK;
                    float* kout = (SK > 1) ? (float*)TEMP : gout;
                    dim3 gr(gx, gy, SK);
#define GL(MTC, KSC, SPL)                                                      \
                    conv_mfma<MTC, KSC, SPL><<<gr, 256, 0, stream>>>(          \
                        cur, WHI + woff, WLO + woff, bb, kout, l.cin, inBS,    \
                        inRow, Hc, Wc, l.cout, l.cpad, b0, nb, nkb, nkbPer,    \
                        Mpad, gBS, gRow)
#define G2(MTC, KSC) do { if (SK > 1) GL(MTC, KSC, true); else GL(MTC, KSC, false); } while (0)
                    if (MTv == 4)      { if (l.ks == 3) G2(4, 3); else G2(4, 1); }
                    else if (MTv == 2) { if (l.ks == 3) G2(2, 3); else G2(2, 1); }
                    else               { if (l.ks == 3) G2(1, 3); else G2(1, 1); }
#undef G2
#undef GL
                    if (SK > 1) {
                        int tot4 = M * (l.cout / 4);
                        sk_reduce<<<(tot4 + 255) / 256, 256, 0, stream>>>(
                            (const float*)TEMP, bb, dst, l.cout, Hc * Wc, Wc,
                            M, Mpad, SK, outBS, outRow);
                    }
                }
                if (l.pool) {
                    int total4 = nb * (Hout + 2) * (Wout + 2) * (l.cout / 4);
                    // only interior written; iterate interior via Hp=Hout,Wp=Wout
                    total4 = nb * Hout * Wout * (l.cout / 4);
                    maxpool_k<<<(total4 + 255) / 256, 256, 0, stream>>>(
                        (const float*)TEMP, dst, Hc, Wc, Hout, Wout, l.ppad,
                        total4, l.cout, tBS, tRow, outBS, outRow, b0);
                }
            }
        } else {
            const int spatial = Hout * Wout;
            // strides for conv_fused (generalized)
            long iBS, iCS, iOfs; int iRS, iXS;
            if (i == 0) { iBS = (long)l.cin * Hin * Win; iCS = (long)Hin * Win;
                          iRS = Win; iXS = 1; iOfs = 0; }
            else        { iBS = inBS; iCS = 1; iRS = inRow; iXS = l.cin;
                          iOfs = (long)inRow + l.cin; }
            long oBS, oCS, oOfs; int oRS, oXS;
            if (i == 17) { oBS = (long)l.cout * spatial; oCS = spatial;
                           oRS = Wout; oXS = 1; oOfs = 0; }
            else         { oBS = outBS; oCS = 1; oRS = outRow; oXS = l.cout;
                           oOfs = (long)outRow + l.cout; }
#define FL(KK, CC, PP, MM, SW)                                                 \
            conv_fused<KK, CC, PP, MM, SW><<<                                  \
                SW ? dim3(l.cout / CC, (B * spatial + 255) / 256)              \
                   : dim3((B * spatial + 255) / 256, l.cout / CC),             \
                256, 0, stream>>>(                                             \
                cur, w, bb, dst, B, l.cin, Hin, Win, Hc, Wc, Hout, Wout,       \
                l.cout, l.cpad, l.ppad,                                        \
                iBS, iCS, iRS, iXS, iOfs, oBS, oCS, oRS, oXS, oOfs)
            if (i == 0)                           FL(3, 8, true, true, true);
            else if (i == 16)                     FL(1, 8, false, false, false);
            else if (i == 17)                     FL(3, 6, false, false, false);
            else if (l.pool)                      FL(3, 8, true, true, false);
            else if (l.ks == 3)                   FL(3, 8, false, true, false);
            else                                  FL(1, 8, false, true, false);
#undef FL
        }

        if (i >= 1 && i <= 15) woff += (size_t)l.cout * kdim;
        cur = dst;
        Hin = Hout;
        Win = Wout;
    }

    head_kernel<<<1, 1024, 0, stream>>>(cur, (float*)d_out, B);
}